// Round 11
// baseline (90.306 us; speedup 1.0000x reference)
//
#include <hip/hip_runtime.h>
#include <math.h>

// BispectrumCalculator:
//   y = fft(target)  [B,T,N] complex
//   Bx[k,l] = y[k] * conj(y[l]) * y[(l-k) mod N]
//   source = stack([Bx.re, Bx.im], ch).mean(T)  -> [B, 2, N, N]
//   outputs: (source, target)  -> d_out = source flat (16,777,216) ++ target flat (65,536)
//
// Window model (r2-r14): harness re-poison of d_ws (257 MiB) + d_out
// (64 MiB) is inside the measured window (fills at ~6 TB/s, top-5 is all
// fills); controllable slice (dft + bispec + gaps) ~29us of the 86us
// window.
//
// History: r7 = 87.1. r8 = 169 (min-waves hint -> 64 VGPR -> spills;
// NEVER re-add). r9/r10 = 90.9 (K=8xC=4 occupancy tail). r11 = 86.0
// (single 16 KiB swizzled ring). r12 = 85.95 (kk-outer early stores,
// IDENTICAL -> bispec insensitive to LDS/store schedule). r13 = 86.3
// (dft overhaul: 2x TLP + sincosf 5->2, flat -> dft was already ~3us).
//
// r14/r15/r16: SINGLE-VARIABLE test of the write path. Hypothesis: bispec
// is pinned ~20us (3.2 TB/s) by L2 write-allocate thrash (64 MiB streamed
// through 32 MiB L2), while fillBuffer hits 6 TB/s via nontemporal
// semantics. Change: __builtin_nontemporal_store on all output stores
// (bispec 8x float4, dft tail passthrough). Everything else is
// byte-identical to r13. Flat result => bispec at true HBM write floor
// => ROOFLINE.   (r15 fixed the builtin's type: it requires a NATIVE
// clang vector pointer, not HIP_vector_type<float,4>*. r16 = r15 verbatim;
// r15's bench died on container acquire, not the kernel.)

#define NN 512
#define TT 4
#define BB 32

// native clang vector for nontemporal builtins (layout-identical to float4)
typedef float nt_f4 __attribute__((ext_vector_type(4)));

__device__ __forceinline__ void nt_store4(void* p, float a, float b, float c, float d) {
    nt_f4 v = {a, b, c, d};
    __builtin_nontemporal_store(v, (nt_f4*)p);
}

__device__ __forceinline__ void nt_copy4(void* dst, const float4 s) {
    nt_f4 v = {s.x, s.y, s.z, s.w};
    __builtin_nontemporal_store(v, (nt_f4*)dst);
}

// bijective within each 64-entry (512 B) float2 tile
__device__ __forceinline__ int sw_idx(int idx) {
    return (idx & ~63) | ((idx & 3) << 4) | ((idx >> 2) & 15);
}

__device__ __forceinline__ float2 cmul(float2 a, float2 b) {
    return make_float2(a.x * b.x - a.y * b.y, a.x * b.y + a.y * b.x);
}

// ---------------------------------------------------------------------------
// Kernel A: Hermitian DFT-512 per (b,t)  (structure unchanged from r13).
// Grid = 128 bt x 8 kq = 1024 blocks, 256 threads = 32 kl x 8 nh.
// k = kq*32 + kl in [0,256); each thread sums n in [nh*64, nh*64+64).
// 2 sincosf seeds + cmul-derived twiddles; nh partials combined in LDS;
// nh==0 stores y[k] and conj to y[512-k]. kq==0 also computes y[256]
// (alternating sum) and copies the target row to the output tail.
// ---------------------------------------------------------------------------
__global__ __launch_bounds__(256) void dft_kernel(const float* __restrict__ x,
                                                  float2* __restrict__ y,
                                                  float* __restrict__ tail) {
    __shared__ float2 part[224];      // nh = 1..7 partials, [nh-1][kl]
    __shared__ float  salt[8];        // alternating-sum partials per nh

    int bt = blockIdx.x >> 3;
    int kq = blockIdx.x & 7;
    int kl = threadIdx.x & 31;
    int nh = threadIdx.x >> 5;
    int k  = (kq << 5) | kl;          // [0,256)
    const float* xp = x + (size_t)bt * NN;

    if (kq == 0 && nh == 0) {
        // target passthrough: 32 lanes x 4 float4 = 2 KiB row (nt stores)
        float4* tp = (float4*)(tail + (size_t)bt * NN);
        const float4* sp = (const float4*)xp;
        nt_copy4(tp + kl,      sp[kl]);
        nt_copy4(tp + kl + 32, sp[kl + 32]);
        nt_copy4(tp + kl + 64, sp[kl + 64]);
        nt_copy4(tp + kl + 96, sp[kl + 96]);
    }

    int n0 = nh << 6;  // 0,64,...,448
    const float tw = -2.0f * (float)M_PI / (float)NN;

    // seeds: 2 sincosf + 5 cmul
    float2 w0, u;
    {
        int m0 = (k * n0) & (NN - 1);
        sincosf(tw * (float)m0, &w0.y, &w0.x);
        sincosf(tw * (float)k,  &u.y,  &u.x);
    }
    float2 u2 = cmul(u, u);
    float2 u4 = cmul(u2, u2);
    float2 w1 = cmul(w0, u);
    float2 w2 = cmul(w0, u2);
    float2 w3 = cmul(w1, u2);
    float c4 = u4.x, s4 = u4.y;

    float2 a0 = make_float2(0.f, 0.f), a1 = a0, a2 = a0, a3 = a0;
    float sa = 0.f;  // alternating sum partial (kq==0 only)

    const float4* xp4 = (const float4*)xp;
    int i4 = n0 >> 2;

    if (kq == 0) {
        #pragma unroll 4
        for (int it = 0; it < 16; ++it) {
            float4 xv = xp4[i4 + it];         // uniform 16B broadcast fetch
            sa += (xv.x - xv.y) + (xv.z - xv.w);  // n0 even -> +,-,+,-
            a0.x += xv.x * w0.x; a0.y += xv.x * w0.y;
            a1.x += xv.y * w1.x; a1.y += xv.y * w1.y;
            a2.x += xv.z * w2.x; a2.y += xv.z * w2.y;
            a3.x += xv.w * w3.x; a3.y += xv.w * w3.y;
            float t;
            t = w0.x * c4 - w0.y * s4; w0.y = w0.x * s4 + w0.y * c4; w0.x = t;
            t = w1.x * c4 - w1.y * s4; w1.y = w1.x * s4 + w1.y * c4; w1.x = t;
            t = w2.x * c4 - w2.y * s4; w2.y = w2.x * s4 + w2.y * c4; w2.x = t;
            t = w3.x * c4 - w3.y * s4; w3.y = w3.x * s4 + w3.y * c4; w3.x = t;
        }
    } else {
        #pragma unroll 4
        for (int it = 0; it < 16; ++it) {
            float4 xv = xp4[i4 + it];
            a0.x += xv.x * w0.x; a0.y += xv.x * w0.y;
            a1.x += xv.y * w1.x; a1.y += xv.y * w1.y;
            a2.x += xv.z * w2.x; a2.y += xv.z * w2.y;
            a3.x += xv.w * w3.x; a3.y += xv.w * w3.y;
            float t;
            t = w0.x * c4 - w0.y * s4; w0.y = w0.x * s4 + w0.y * c4; w0.x = t;
            t = w1.x * c4 - w1.y * s4; w1.y = w1.x * s4 + w1.y * c4; w1.x = t;
            t = w2.x * c4 - w2.y * s4; w2.y = w2.x * s4 + w2.y * c4; w2.x = t;
            t = w3.x * c4 - w3.y * s4; w3.y = w3.x * s4 + w3.y * c4; w3.x = t;
        }
    }

    float re = (a0.x + a1.x) + (a2.x + a3.x);
    float im = (a0.y + a1.y) + (a2.y + a3.y);

    if (nh) {
        part[((nh - 1) << 5) + kl] = make_float2(re, im);
    }
    if (kq == 0 && kl == 0) {
        salt[nh] = sa;
    }
    __syncthreads();

    if (nh == 0) {
        float rr = re, ii = im;
        #pragma unroll
        for (int i = 0; i < 7; ++i) {
            float2 p = part[(i << 5) + kl];
            rr += p.x; ii += p.y;
        }
        float2* yb = y + (size_t)bt * NN;
        yb[k] = make_float2(rr, ii);
        if (k != 0) {
            yb[NN - k] = make_float2(rr, -ii);   // Hermitian mirror
        }
        if (kq == 0 && kl == 0) {
            float s = ((salt[0] + salt[1]) + (salt[2] + salt[3]))
                    + ((salt[4] + salt[5]) + (salt[6] + salt[7]));
            yb[NN / 2] = make_float2(s, 0.f);
        }
    }
}

// ---------------------------------------------------------------------------
// Kernel B: bispectrum (structure byte-identical to r12/r13; stores are
// now NONTEMPORAL). Grid = B * 64 = 2048 blocks x 256 threads. Block =
// one b, 8 consecutive k-rows, all 512 cols. Thread = 4 rows x 4 ADJACENT
// cols. kk-OUTER / t-INNER with immediate per-row stores. bb[t][c]
// hoisted to regs; per kk only its 4-wide slice of the 7-window is read;
// av is a wave-uniform broadcast. Single swizzled 16 KiB ring, wrap
// folded into precomputed indices:
//     sw(idx) = (idx&~63) | ((idx&3)<<4) | ((idx>>2)&15)
// ---------------------------------------------------------------------------
__global__ __launch_bounds__(256) void bispec_kernel(const float2* __restrict__ y,
                                                     float* __restrict__ out) {
    __shared__ float2 ring[TT * NN];  // 16 KiB, swizzled, single copy

    int b   = blockIdx.x >> 6;
    int kb  = blockIdx.x & 63;   // 8-row group
    int tid = threadIdx.x;

    // stage y[b] -> swizzled ring (global: [t][256] float4)
    const float4* src = (const float4*)(y + (size_t)b * TT * NN);
    #pragma unroll
    for (int i = 0; i < 4; ++i) {
        int g = tid + 256 * i;          // [0,1024)
        int t = g >> 8;
        int j = g & 255;                // float4 index within t-row (512 float2)
        float4 v = src[g];
        int s0 = sw_idx((t << 9) + 2 * j);   // 2j even -> sw(2j+1)=sw(2j)+16
        ring[s0]      = make_float2(v.x, v.y);
        ring[s0 + 16] = make_float2(v.z, v.w);
    }
    __syncthreads();

    int kg    = tid >> 7;            // wave-uniform (waves 0,1 -> 0; 2,3 -> 1)
    int ll    = tid & 127;
    int l0    = ll << 2;             // 4 adjacent columns l0..l0+3
    int kbase = (kb << 3) | (kg << 2);  // this thread's 4 rows (kbase%4==0)

    // swizzled t=0 indices (wrap folded in), reused across t via +t*512
    int w0 = (l0 - kbase - 3) & (NN - 1);  // window start
    int swj[7];
    #pragma unroll
    for (int j = 0; j < 7; ++j) swj[j] = sw_idx((w0 + j) & (NN - 1));
    int sa0 = sw_idx(kbase);  // kbase%4==0 -> av[kk] at sa0 + (kk<<4)
    int sb0 = sw_idx(l0);     // l0%4==0   -> bb[c]  at sb0 + (c<<4)

    // hoist kk-invariant conj-source values: bb[t][c] (32 VGPR)
    float2 bbr[TT][4];
    #pragma unroll
    for (int t = 0; t < TT; ++t)
        #pragma unroll
        for (int c = 0; c < 4; ++c)
            bbr[t][c] = ring[(t << 9) + sb0 + (c << 4)];

    float* outb = out + (size_t)b * 2 * NN * NN;

    #pragma unroll
    for (int kk = 0; kk < 4; ++kk) {
        float r[4] = {0.f, 0.f, 0.f, 0.f};
        float q[4] = {0.f, 0.f, 0.f, 0.f};

        #pragma unroll
        for (int t = 0; t < TT; ++t) {
            const float2* rt = ring + (t << 9);
            float2 a  = rt[sa0 + (kk << 4)];   // wave-uniform broadcast
            float2 cw0 = rt[swj[3 - kk + 0]];  // lane-spread, conflict-free
            float2 cw1 = rt[swj[3 - kk + 1]];
            float2 cw2 = rt[swj[3 - kk + 2]];
            float2 cw3 = rt[swj[3 - kk + 3]];
            float2 cwv[4] = {cw0, cw1, cw2, cw3};
            #pragma unroll
            for (int c = 0; c < 4; ++c) {
                float2 cv = cwv[c];           // = y_t[(l0+c - kbase-kk) mod 512]
                float2 bv = bbr[t][c];        // = y_t[l0+c]
                float ur = a.x * cv.x - a.y * cv.y;
                float ui = a.x * cv.y + a.y * cv.x;
                r[c] += ur * bv.x + ui * bv.y;   // Re(a*cv*conj(bv))
                q[c] += ui * bv.x - ur * bv.y;   // Im(a*cv*conj(bv))
            }
        }

        // store this k-row immediately, NONTEMPORAL (bypass L2 allocate)
        size_t rk = (size_t)(kbase + kk) * NN + l0;
        nt_store4(outb + rk,
                  r[0] * 0.25f, r[1] * 0.25f, r[2] * 0.25f, r[3] * 0.25f);
        nt_store4(outb + (size_t)NN * NN + rk,
                  q[0] * 0.25f, q[1] * 0.25f, q[2] * 0.25f, q[3] * 0.25f);
    }
}

extern "C" void kernel_launch(void* const* d_in, const int* in_sizes, int n_in,
                              void* d_out, int out_size, void* d_ws, size_t ws_size,
                              hipStream_t stream) {
    const float* target = (const float*)d_in[0];
    float* out = (float*)d_out;
    // workspace: y spectrum, B*T*N complex64 = 512 KiB
    float2* y = (float2*)d_ws;
    float* tail = out + (size_t)BB * 2 * NN * NN;  // target passthrough

    dft_kernel<<<BB * TT * 8, 256, 0, stream>>>(target, y, tail);
    bispec_kernel<<<BB * 64, 256, 0, stream>>>(y, out);
}

// Round 12
// 86.959 us; speedup vs baseline: 1.0385x; 1.0385x over previous
//
#include <hip/hip_runtime.h>
#include <math.h>

// BispectrumCalculator:
//   y = fft(target)  [B,T,N] complex
//   Bx[k,l] = y[k] * conj(y[l]) * y[(l-k) mod N]
//   source = stack([Bx.re, Bx.im], ch).mean(T)  -> [B, 2, N, N]
//   outputs: (source, target)  -> d_out = source flat (16,777,216) ++ target flat (65,536)
//
// FINAL (r17 = r12 verbatim, the session best: 85.95us).
//
// Window model: harness re-poison of d_ws (257 MiB, ~46us at 74% peak) +
// d_out (64 MiB, ~11us) is inside the measured window; d_out write floor
// ~11us + dft ~3us + dispatch gaps ~5us => ~86us total. Three structurally
// distinct schedules (r11/r12/r13) all land at 86.0 +/- 0.35 -> external
// floor, not kernel-limited.
//
// Probed and settled:
//  r8:  min-waves hint -> 64 VGPR bucket -> spills -> 169us. NEVER re-add.
//  r9:  K=8xC=4 -> VGPR>128 -> occupancy tail -> 90.9. Tile wider loses.
//  r11: single 16 KiB swizzled ring (wrap folded into precomputed idx).
//  r12: kk-outer early stores == r11 -> insensitive to LDS/store schedule.
//  r13: dft 2x TLP + sincosf 5->2 -> flat (dft was already ~3us).
//  r16: NONTEMPORAL stores -> 90.3 (+4). L2-cached stores are optimal;
//       nt bypasses L2's store buffering. NEVER use nt here.

#define NN 512
#define TT 4
#define BB 32

// bijective within each 64-entry (512 B) float2 tile
__device__ __forceinline__ int sw_idx(int idx) {
    return (idx & ~63) | ((idx & 3) << 4) | ((idx >> 2) & 15);
}

// ---------------------------------------------------------------------------
// Kernel A: Hermitian DFT-512 per (b,t).
// Grid = 128 bt x 4 kq = 512 blocks, 256 threads = 64 kl x 4 nh.
// k = kq*64 + kl in [0,256); each thread sums n in [nh*128, nh*128+128).
// Rotor seeds via exact mod-512 phase reduction; nh partials combined in
// LDS; nh==0 stores y[k] and conj to y[512-k]. kq==0 also computes y[256]
// (alternating sum, +1 FMA/n) and copies the target row to the output tail.
// ---------------------------------------------------------------------------
__global__ __launch_bounds__(256) void dft_kernel(const float* __restrict__ x,
                                                  float2* __restrict__ y,
                                                  float* __restrict__ tail) {
    __shared__ float2 part[192];      // nh = 1..3 partials, [nh-1][kl]
    __shared__ float  salt[4];        // alternating-sum partials per nh

    int bt = blockIdx.x >> 2;
    int kq = blockIdx.x & 3;
    int kl = threadIdx.x & 63;
    int nh = threadIdx.x >> 6;
    int k  = (kq << 6) | kl;          // [0,256)
    const float* xp = x + (size_t)bt * NN;

    if (kq == 0 && nh == 0) {
        // target passthrough: 64 lanes x 2 float4 = 2 KiB row
        ((float4*)(tail + (size_t)bt * NN))[kl]      = ((const float4*)xp)[kl];
        ((float4*)(tail + (size_t)bt * NN))[kl + 64] = ((const float4*)xp)[kl + 64];
    }

    int n0 = nh << 7;  // 0,128,256,384
    const float twopi_n = -2.0f * (float)M_PI / (float)NN;

    float2 w0, w1, w2, w3;
    float s4, c4;
    {
        int m0 = (k * (n0 + 0)) & (NN - 1);
        int m1 = (k * (n0 + 1)) & (NN - 1);
        int m2 = (k * (n0 + 2)) & (NN - 1);
        int m3 = (k * (n0 + 3)) & (NN - 1);
        int m4 = (k * 4) & (NN - 1);
        sincosf(twopi_n * (float)m0, &w0.y, &w0.x);
        sincosf(twopi_n * (float)m1, &w1.y, &w1.x);
        sincosf(twopi_n * (float)m2, &w2.y, &w2.x);
        sincosf(twopi_n * (float)m3, &w3.y, &w3.x);
        sincosf(twopi_n * (float)m4, &s4, &c4);
    }

    float2 a0 = make_float2(0.f, 0.f), a1 = a0, a2 = a0, a3 = a0;
    float sa = 0.f;  // alternating sum partial (kq==0 only)

    if (kq == 0) {
        #pragma unroll 4
        for (int n = n0; n < n0 + 128; n += 4) {
            float x0 = xp[n];
            float x1 = xp[n + 1];
            float x2 = xp[n + 2];
            float x3 = xp[n + 3];
            sa += (x0 - x1) + (x2 - x3);   // n0 even -> signs +,-,+,-
            a0.x += x0 * w0.x; a0.y += x0 * w0.y;
            a1.x += x1 * w1.x; a1.y += x1 * w1.y;
            a2.x += x2 * w2.x; a2.y += x2 * w2.y;
            a3.x += x3 * w3.x; a3.y += x3 * w3.y;
            float t;
            t = w0.x * c4 - w0.y * s4; w0.y = w0.x * s4 + w0.y * c4; w0.x = t;
            t = w1.x * c4 - w1.y * s4; w1.y = w1.x * s4 + w1.y * c4; w1.x = t;
            t = w2.x * c4 - w2.y * s4; w2.y = w2.x * s4 + w2.y * c4; w2.x = t;
            t = w3.x * c4 - w3.y * s4; w3.y = w3.x * s4 + w3.y * c4; w3.x = t;
        }
    } else {
        #pragma unroll 4
        for (int n = n0; n < n0 + 128; n += 4) {
            float x0 = xp[n];
            float x1 = xp[n + 1];
            float x2 = xp[n + 2];
            float x3 = xp[n + 3];
            a0.x += x0 * w0.x; a0.y += x0 * w0.y;
            a1.x += x1 * w1.x; a1.y += x1 * w1.y;
            a2.x += x2 * w2.x; a2.y += x2 * w2.y;
            a3.x += x3 * w3.x; a3.y += x3 * w3.y;
            float t;
            t = w0.x * c4 - w0.y * s4; w0.y = w0.x * s4 + w0.y * c4; w0.x = t;
            t = w1.x * c4 - w1.y * s4; w1.y = w1.x * s4 + w1.y * c4; w1.x = t;
            t = w2.x * c4 - w2.y * s4; w2.y = w2.x * s4 + w2.y * c4; w2.x = t;
            t = w3.x * c4 - w3.y * s4; w3.y = w3.x * s4 + w3.y * c4; w3.x = t;
        }
    }

    float re = (a0.x + a1.x) + (a2.x + a3.x);
    float im = (a0.y + a1.y) + (a2.y + a3.y);

    if (nh) {
        part[((nh - 1) << 6) + kl] = make_float2(re, im);
    }
    if (kq == 0 && kl == 0) {
        salt[nh] = sa;
    }
    __syncthreads();

    if (nh == 0) {
        float2 p0 = part[kl];
        float2 p1 = part[64 + kl];
        float2 p2 = part[128 + kl];
        float rr = ((re + p0.x) + (p1.x + p2.x));
        float ii = ((im + p0.y) + (p1.y + p2.y));
        float2* yb = y + (size_t)bt * NN;
        yb[k] = make_float2(rr, ii);
        if (k != 0) {
            yb[NN - k] = make_float2(rr, -ii);   // Hermitian mirror
        }
        if (kq == 0 && kl == 0) {
            yb[NN / 2] = make_float2((salt[0] + salt[1]) + (salt[2] + salt[3]), 0.f);
        }
    }
}

// ---------------------------------------------------------------------------
// Kernel B: bispectrum. Grid = B * 64 = 2048 blocks x 256 threads.
// Block = one b, 8 consecutive k-rows, all 512 cols. Thread = 4 rows x 4
// ADJACENT cols. kk-OUTER / t-INNER with immediate per-row stores.
// bb[t][c] hoisted to regs; per kk only its 4-wide slice of the 7-window
// is read; av is a wave-uniform broadcast. Single swizzled 16 KiB ring,
// wrap folded into precomputed indices:
//     sw(idx) = (idx&~63) | ((idx&3)<<4) | ((idx>>2)&15)
// Plain cached stores (r16 proved nt stores cost +4us).
// ---------------------------------------------------------------------------
__global__ __launch_bounds__(256) void bispec_kernel(const float2* __restrict__ y,
                                                     float* __restrict__ out) {
    __shared__ float2 ring[TT * NN];  // 16 KiB, swizzled, single copy

    int b   = blockIdx.x >> 6;
    int kb  = blockIdx.x & 63;   // 8-row group
    int tid = threadIdx.x;

    // stage y[b] -> swizzled ring (global: [t][256] float4)
    const float4* src = (const float4*)(y + (size_t)b * TT * NN);
    #pragma unroll
    for (int i = 0; i < 4; ++i) {
        int g = tid + 256 * i;          // [0,1024)
        int t = g >> 8;
        int j = g & 255;                // float4 index within t-row (512 float2)
        float4 v = src[g];
        int s0 = sw_idx((t << 9) + 2 * j);   // 2j even -> sw(2j+1)=sw(2j)+16
        ring[s0]      = make_float2(v.x, v.y);
        ring[s0 + 16] = make_float2(v.z, v.w);
    }
    __syncthreads();

    int kg    = tid >> 7;            // wave-uniform (waves 0,1 -> 0; 2,3 -> 1)
    int ll    = tid & 127;
    int l0    = ll << 2;             // 4 adjacent columns l0..l0+3
    int kbase = (kb << 3) | (kg << 2);  // this thread's 4 rows (kbase%4==0)

    // swizzled t=0 indices (wrap folded in), reused across t via +t*512
    int w0 = (l0 - kbase - 3) & (NN - 1);  // window start
    int swj[7];
    #pragma unroll
    for (int j = 0; j < 7; ++j) swj[j] = sw_idx((w0 + j) & (NN - 1));
    int sa0 = sw_idx(kbase);  // kbase%4==0 -> av[kk] at sa0 + (kk<<4)
    int sb0 = sw_idx(l0);     // l0%4==0   -> bb[c]  at sb0 + (c<<4)

    // hoist kk-invariant conj-source values: bb[t][c] (32 VGPR)
    float2 bbr[TT][4];
    #pragma unroll
    for (int t = 0; t < TT; ++t)
        #pragma unroll
        for (int c = 0; c < 4; ++c)
            bbr[t][c] = ring[(t << 9) + sb0 + (c << 4)];

    float* outb = out + (size_t)b * 2 * NN * NN;

    #pragma unroll
    for (int kk = 0; kk < 4; ++kk) {
        float r[4] = {0.f, 0.f, 0.f, 0.f};
        float q[4] = {0.f, 0.f, 0.f, 0.f};

        #pragma unroll
        for (int t = 0; t < TT; ++t) {
            const float2* rt = ring + (t << 9);
            float2 a  = rt[sa0 + (kk << 4)];   // wave-uniform broadcast
            float2 cw0 = rt[swj[3 - kk + 0]];  // lane-spread, conflict-free
            float2 cw1 = rt[swj[3 - kk + 1]];
            float2 cw2 = rt[swj[3 - kk + 2]];
            float2 cw3 = rt[swj[3 - kk + 3]];
            float2 cwv[4] = {cw0, cw1, cw2, cw3};
            #pragma unroll
            for (int c = 0; c < 4; ++c) {
                float2 cv = cwv[c];           // = y_t[(l0+c - kbase-kk) mod 512]
                float2 bv = bbr[t][c];        // = y_t[l0+c]
                float ur = a.x * cv.x - a.y * cv.y;
                float ui = a.x * cv.y + a.y * cv.x;
                r[c] += ur * bv.x + ui * bv.y;   // Re(a*cv*conj(bv))
                q[c] += ui * bv.x - ur * bv.y;   // Im(a*cv*conj(bv))
            }
        }

        // store this k-row immediately -> overlaps later kk's compute
        size_t rk = (size_t)(kbase + kk) * NN + l0;
        float4 vr = make_float4(r[0] * 0.25f, r[1] * 0.25f,
                                r[2] * 0.25f, r[3] * 0.25f);
        float4 vq = make_float4(q[0] * 0.25f, q[1] * 0.25f,
                                q[2] * 0.25f, q[3] * 0.25f);
        *(float4*)(outb + rk)                   = vr;  // real ch
        *(float4*)(outb + (size_t)NN * NN + rk) = vq;  // imag ch
    }
}

extern "C" void kernel_launch(void* const* d_in, const int* in_sizes, int n_in,
                              void* d_out, int out_size, void* d_ws, size_t ws_size,
                              hipStream_t stream) {
    const float* target = (const float*)d_in[0];
    float* out = (float*)d_out;
    // workspace: y spectrum, B*T*N complex64 = 512 KiB
    float2* y = (float2*)d_ws;
    float* tail = out + (size_t)BB * 2 * NN * NN;  // target passthrough

    dft_kernel<<<BB * TT * 4, 256, 0, stream>>>(target, y, tail);
    bispec_kernel<<<BB * 64, 256, 0, stream>>>(y, out);
}